// Round 19
// baseline (138.177 us; speedup 1.0000x reference)
//
#include <hip/hip_runtime.h>
#include <hip/hip_bf16.h>
#include <stdint.h>

// Problem constants
#define NHEADS 8
#define KDIM   32
#define HDIM   64
#define CDIM   512
#define HWN    1024
#define BATCH  16
#define QKVCH  1024
#define SCALE_F 0.17677669529663687f  // 32^-0.5
// q pre-scale: SCALE * log2(e), so softmax uses v_exp_f32 (2^x) directly
#define QSCALE_F (0.17677669529663687f * 1.44269504088896341f)

typedef __attribute__((ext_vector_type(8))) short short8;   // 8 bf16 (4 VGPRs)
typedef __attribute__((ext_vector_type(4))) float f32x4;

static __device__ __forceinline__ unsigned short f2bf(float f) {
    unsigned int u = __float_as_uint(f);
    unsigned int r = (u + 0x7fffu + ((u >> 16) & 1u)) >> 16;  // RNE
    return (unsigned short)r;
}
static __device__ __forceinline__ float bf2f(unsigned short h) {
    return __uint_as_float(((unsigned int)h) << 16);
}
// v_cvt_pk_bf16_f32: lo<-a, hi<-b (RNE), 1 instr for 2 converts
static __device__ __forceinline__ unsigned int cvtpk(float a, float b) {
    unsigned int r;
    asm("v_cvt_pk_bf16_f32 %0, %1, %2" : "=v"(r) : "v"(a), "v"(b));
    return r;
}
static __device__ __forceinline__ float fexp2(float x) {
    float r;
    asm("v_exp_f32 %0, %1" : "=v"(r) : "v"(x));
    return r;
}
// static-index bf16 extraction from a uint4 (8 bf16); j must be compile-time
static __device__ __forceinline__ float bfelem(const uint4& v, int j) {
    unsigned int w = ((j >> 1) == 0) ? v.x : ((j >> 1) == 1) ? v.y : ((j >> 1) == 2) ? v.z : v.w;
    return (j & 1) ? __uint_as_float(w & 0xffff0000u) : __uint_as_float(w << 16);
}
// add two bf16 pairs (packed u32) in fp32, repack
static __device__ __forceinline__ unsigned int addpk(unsigned int a, unsigned int p) {
    float lo = __uint_as_float(a << 16) + __uint_as_float(p << 16);
    float hi = __uint_as_float(a & 0xffff0000u) + __uint_as_float(p & 0xffff0000u);
    return cvtpk(lo, hi);
}

// async global->LDS, 16B per lane. LDS dest is wave-uniform base; HW adds lane*16.
static __device__ __forceinline__ void gload_lds16(const void* g, void* l) {
    __builtin_amdgcn_global_load_lds(
        (const __attribute__((address_space(1))) void*)g,
        (__attribute__((address_space(3))) void*)l, 16, 0, 0);
}

// ---------------- fused preprocessing: transpose + both weight converts ----------------
// blocks [0,2048): transpose x (b,c,n) fp32 -> xt (b,n,c) bf16
// blocks [2048,2304): convert w_qkv (524288 elems); [2304,2432): convert w_out (262144)
__global__ __launch_bounds__(256) void pre_kernel(
    const float* __restrict__ x, unsigned short* __restrict__ xt,
    const float* __restrict__ wq, unsigned short* __restrict__ wqb,
    const float* __restrict__ wo, unsigned short* __restrict__ wob) {
    __shared__ unsigned short tl[64][66];   // pad 66: odd word stride -> spread banks
    int bid = blockIdx.x;
    int t = threadIdx.x;
    if (bid < 2048) {
        int b = bid >> 7, ct = (bid >> 4) & 7, nt = bid & 15;
#pragma unroll
        for (int i = 0; i < 16; ++i) {
            int idx = i * 256 + t;
            int cl = idx >> 6, nl = idx & 63;
            tl[cl][nl] = f2bf(x[((size_t)(b * CDIM + ct * 64 + cl)) * HWN + nt * 64 + nl]);
        }
        __syncthreads();
        int a8 = (t & 7) * 8;
        int nl = t >> 3;
#pragma unroll
        for (int i = 0; i < 2; ++i) {
            int n = nt * 64 + nl + 32 * i;
            unsigned short tmp[8] __attribute__((aligned(16)));
#pragma unroll
            for (int j = 0; j < 8; ++j) tmp[j] = tl[a8 + j][nl + 32 * i];
            *(uint4*)(xt + ((size_t)b * HWN + n) * CDIM + ct * 64 + a8) = *(const uint4*)tmp;
        }
    } else {
        const float* src = (bid < 2304) ? wq : wo;
        unsigned short* dst = (bid < 2304) ? wqb : wob;
        int rb = (bid < 2304) ? (bid - 2048) : (bid - 2304);
        int i = (rb * 256 + t) * 8;
        float4 a = *(const float4*)(src + i);
        float4 c = *(const float4*)(src + i + 4);
        unsigned short r[8] __attribute__((aligned(16))) =
            {f2bf(a.x), f2bf(a.y), f2bf(a.z), f2bf(a.w), f2bf(c.x), f2bf(c.y), f2bf(c.z), f2bf(c.w)};
        *(uint4*)(dst + i) = *(const uint4*)r;
    }
}

// ---------------- bf16 GEMM, BM=256 x BN tile, templated BK, 8 waves (512 thr) ----------------
// Treats the batched problem as M x (16*1024) columns. A: (M x 512) bf16 weights.
// Bt: (16, 1024, 512) bf16 (K contig). D[o][b,n] = sum_k A[o][k]*Bt[n][k].
// Fragment-ordered LDS (lane-linear ds_read_b128, 0 conflicts), double-buffered.
// BK=32 + BN=256 (R16 best config). T1: xcd = p&7 owns batches {2*xcd, 2*xcd+1}.
template <int MODE, int BN, int BK, int WM, int WN, int NTB>
__global__ __launch_bounds__(512, 2) void gemm_bf16(
    const unsigned short* __restrict__ A, const unsigned short* __restrict__ Bt,
    const float* __restrict__ gvec, const float* __restrict__ bvec,
    void* out0, void* out1, void* out2) {
    constexpr int MF = 256 / (16 * WM);      // m-frags per wave
    constexpr int NF = BN / (16 * WN);       // n-frags per wave
    constexpr int BUFE = (256 + BN) * BK;    // elems per LDS buffer
    constexpr int AIT = BK / 16;             // stage_a loop count (A units = 32*BK)
    constexpr int BUNITS = BN * BK / 4096;   // stage_b loop count
    constexpr int PHB = BN * 4;              // B units per 32-k half
    constexpr int AELEMS = 256 * BK;         // A region elems
    constexpr int KT = 512 / BK;             // K-tiles
    __shared__ unsigned short lds[2][BUFE];

    int p = blockIdx.x;
    int xcd = p & 7;
    int j2 = p >> 3;                         // 0..31
    int b = xcd * 2 + (j2 >= 16 ? 1 : 0);
    int idx = j2 & 15;
    int mt = idx / NTB, ntl = idx % NTB;
    int t = threadIdx.x, lane = t & 63, w = t >> 6, g = lane >> 4, lr = lane & 15;
    int M0 = mt * 256, N0 = ntl * BN;
    int wr = (w / WN) * (16 * MF), wc = (w % WN) * (16 * NF);

    const unsigned short* Ab = A + (size_t)M0 * 512;
    const unsigned short* Bb = Bt + (size_t)b * HWN * 512 + (size_t)N0 * 512;

    auto stage_a = [&](int kt, int buf) {
        unsigned short* base = &lds[buf][0];
#pragma unroll
        for (int i = 0; i < AIT; ++i) {      // A: 256 x BK
            int U0 = i * 512 + w * 64;
            int U = U0 + lane;
            int h = U >> 10, rem = U & 1023;
            int row = ((rem >> 6) << 4) + (lane & 15);
            int k = ((lane >> 4) << 3) + (h << 5);
            gload_lds16(Ab + (size_t)row * 512 + kt * BK + k, (char*)base + U0 * 16);
        }
    };
    auto stage_b = [&](int kt, int buf) {
        unsigned short* base = &lds[buf][0];
#pragma unroll
        for (int i = 0; i < BUNITS; ++i) {   // B: BN x BK
            int U0 = i * 512 + w * 64;
            int U = U0 + lane;
            int h = U / PHB, rem = U % PHB;
            int row = ((rem >> 6) << 4) + (lane & 15);
            int k = ((lane >> 4) << 3) + (h << 5);
            gload_lds16(Bb + (size_t)row * 512 + kt * BK + k,
                        (char*)base + AELEMS * 2 + U0 * 16);
        }
    };

    f32x4 acc[MF][NF] = {};
    stage_a(0, 0);
    stage_b(0, 0);
    __syncthreads();
    for (int kt = 0; kt < KT; ++kt) {
        int cur = kt & 1;
        const unsigned short* base = &lds[cur][0];
        auto compute_h = [&](int h) {
            short8 af[MF], bfr[NF];
#pragma unroll
            for (int i = 0; i < MF; ++i)
                af[i] = *(const short8*)(base + h * 8192 + (((wr >> 4) + i) * 64 + lane) * 8);
#pragma unroll
            for (int j = 0; j < NF; ++j)
                bfr[j] = *(const short8*)(base + AELEMS + h * (BN * 32) +
                                          (((wc >> 4) + j) * 64 + lane) * 8);
#pragma unroll
            for (int i = 0; i < MF; ++i)
#pragma unroll
                for (int j = 0; j < NF; ++j)
                    acc[i][j] = __builtin_amdgcn_mfma_f32_16x16x32_bf16(af[i], bfr[j], acc[i][j], 0, 0, 0);
        };
        if constexpr (BK == 64) {
            if (kt < KT - 1) stage_a(kt + 1, cur ^ 1);
            compute_h(0);
            if (kt < KT - 1) stage_b(kt + 1, cur ^ 1);
            compute_h(1);
        } else {
            if (kt < KT - 1) { stage_a(kt + 1, cur ^ 1); stage_b(kt + 1, cur ^ 1); }
            compute_h(0);
        }
        __syncthreads();
    }

#pragma unroll
    for (int i = 0; i < MF; ++i) {
        int obase = M0 + wr + i * 16 + g * 4;
#pragma unroll
        for (int j = 0; j < NF; ++j) {
            int n = N0 + wc + j * 16 + lr;
            float val[4];
#pragma unroll
            for (int rr = 0; rr < 4; ++rr) {
                int o = obase + rr;
                val[rr] = acc[i][j][rr] * gvec[o] + bvec[o];
            }
            if (MODE == 0) {
                int h = obase >> 7, jj = obase & 127;
                size_t bh = (size_t)((b << 3) + h);
                if (jj < 32) {
                    uint2 pk = {cvtpk(val[0] * QSCALE_F, val[1] * QSCALE_F),
                                cvtpk(val[2] * QSCALE_F, val[3] * QSCALE_F)};
                    *(uint2*)((unsigned short*)out0 + (bh * HWN + n) * KDIM + jj) = pk;
                } else if (jj < 64) {
                    uint2 pk = {cvtpk(val[0], val[1]), cvtpk(val[2], val[3])};
                    *(uint2*)((unsigned short*)out1 + (bh * HWN + n) * KDIM + (jj - 32)) = pk;
                } else {
#pragma unroll
                    for (int rr = 0; rr < 4; ++rr)
                        ((unsigned short*)out2)[(bh * HDIM + (jj - 64 + rr)) * HWN + n] = f2bf(val[rr]);
                }
            } else {
#pragma unroll
                for (int rr = 0; rr < 4; ++rr)
                    ((float*)out0)[((size_t)(b * CDIM + obase + rr)) * HWN + n] = val[rr];
            }
        }
    }
}

// ---------------- flash attention (no-max softmax, 2 q-frags/wave, KVBLK=64) ----------------
// R18 structure with halved K/V tile: LDS 48->24KB so all 4 blocks/CU of the
// grid-1024 launch are co-resident (removes the 1/3-occupancy tail round).
// Fragment/swizzle formulas scale: K chunk c = w (row w*16+lr, kslot g); V unit
// space 8 units/row with the same (u^(dd&7)) involution; reads off0/off1
// reproduce the proven m-slot pattern. m-accumulation order unchanged ->
// bit-identical output. One barrier per tile (16 tiles of 64 rows).
// l is accumulated on the MATRIX pipe (mfma(ones, pf, accl)); accl[0] = l.
// XCD swizzle: p -> bh = ((p>>6)<<3)|(p&7), ntile = (p>>3)&7 (p%8 == bh%8).
// Output: attw (b, n, c=h*64+d) bf16.
__global__ __launch_bounds__(256) void attn_kernel(
    const unsigned short* __restrict__ qw, const unsigned short* __restrict__ kw,
    const unsigned short* __restrict__ vw, unsigned short* __restrict__ attw) {
    __shared__ unsigned short kt[2][64 * 32];   // 2 x 4KB
    __shared__ unsigned short vt[2][64 * 64];   // 2 x 8KB
    int p = blockIdx.x;
    int bh = ((p >> 6) << 3) | (p & 7);
    int ntile = (p >> 3) & 7;
    int b = bh >> 3, h = bh & 7;
    int t = threadIdx.x, lane = t & 63, w = t >> 6, g = lane >> 4, lr = lane & 15;
    int N0 = ntile * 128 + w * 32;
    const unsigned short* qb = qw + (size_t)bh * HWN * KDIM;
    const unsigned short* kb = kw + (size_t)bh * HWN * KDIM;
    const unsigned short* vb = vw + (size_t)bh * HDIM * HWN;

    short8 qf0 = *(const short8*)(qb + (size_t)(N0 + lr) * KDIM + g * 8);
    short8 qf1 = *(const short8*)(qb + (size_t)(N0 + 16 + lr) * KDIM + g * 8);
    f32x4 acc0[4] = {}, acc1[4] = {};
    f32x4 accl0 = {}, accl1 = {};
    f32x4 zero = {0.f, 0.f, 0.f, 0.f};
    short8 onesv;
#pragma unroll
    for (int i = 0; i < 8; ++i) onesv[i] = (short)0x3F80;   // bf16 1.0
    int sw = (lr & 7) << 4;      // V swizzle, constant per lane
    int g8 = g << 3;

    auto stage = [&](int mt, int buf) {
        int M0 = mt * 64;
        // K: 64 rows x 32 k = 4KB = 256 units, 1/thread; unit u=w*64+lane ->
        // c=w, row=w*16+lr, kslot=g (fragment-ordered)
        gload_lds16(kb + (size_t)(M0 + w * 16 + lr) * KDIM + g * 8,
                    (char*)kt[buf] + w * 1024);
        // V: 64 d x 64 m = 8KB = 512 units, 2/thread; source pre-swizzled
#pragma unroll
        for (int i = 0; i < 2; ++i) {
            int s = i * 256 + w * 64 + lane;
            int dd = s >> 3, u = s & 7;
            gload_lds16(vb + (size_t)dd * HWN + M0 + ((u ^ (dd & 7)) << 3),
                        (char*)vt[buf] + (i * 256 + w * 64) * 16);
        }
    };

    stage(0, 0);
    __syncthreads();
    for (int mt = 0; mt < 16; ++mt) {
        int cur = mt & 1;
        if (mt < 15) stage(mt + 1, cur ^ 1);
        const char* ktc = (const char*)kt[cur] + lane * 16;
        const char* vrow = (const char*)vt[cur] + lr * 128;
#pragma unroll
        for (int mc = 0; mc < 2; ++mc) {
            short8 kf0 = *(const short8*)(ktc + mc * 2048);
            short8 kf1 = *(const short8*)(ktc + mc * 2048 + 1024);
            f32x4 s00 = __builtin_amdgcn_mfma_f32_16x16x32_bf16(kf0, qf0, zero, 0, 0, 0);
            f32x4 s01 = __builtin_amdgcn_mfma_f32_16x16x32_bf16(kf1, qf0, zero, 0, 0, 0);
            f32x4 s10 = __builtin_amdgcn_mfma_f32_16x16x32_bf16(kf0, qf1, zero, 0, 0, 0);
            f32x4 s11 = __builtin_amdgcn_mfma_f32_16x16x32_bf16(kf1, qf1, zero, 0, 0, 0);
            float e0[8], e1[8];
#pragma unroll
            for (int i = 0; i < 4; ++i) {
                e0[i] = fexp2(s00[i]); e0[4 + i] = fexp2(s01[i]);
                e1[i] = fexp2(s10[i]); e1[4 + i] = fexp2(s11[i]);
            }
            union { uint4 u; short8 s; } pf0, pf1;
            pf0.u = (uint4){cvtpk(e0[0], e0[1]), cvtpk(e0[2], e0[3]),
                            cvtpk(e0[4], e0[5]), cvtpk(e0[6], e0[7])};
            pf1.u = (uint4){cvtpk(e1[0], e1[1]), cvtpk(e1[2], e1[3]),
                            cvtpk(e1[4], e1[5]), cvtpk(e1[6], e1[7])};
            accl0 = __builtin_amdgcn_mfma_f32_16x16x32_bf16(onesv, pf0.s, accl0, 0, 0, 0);
            accl1 = __builtin_amdgcn_mfma_f32_16x16x32_bf16(onesv, pf1.s, accl1, 0, 0, 0);
            int off0 = (mc * 64 + g8) ^ sw;
            int off1 = off0 ^ 32;
#pragma unroll
            for (int dt = 0; dt < 4; ++dt) {
                uint2 v0 = *(const uint2*)(vrow + dt * 2048 + off0);
                uint2 v1 = *(const uint2*)(vrow + dt * 2048 + off1);
                union { uint2 u[2]; short8 s; } vf;
                vf.u[0] = v0; vf.u[1] = v1;
                acc0[dt] = __builtin_amdgcn_mfma_f32_16x16x32_bf16(vf.s, pf0.s, acc0[dt], 0, 0, 0);
                acc1[dt] = __builtin_amdgcn_mfma_f32_16x16x32_bf16(vf.s, pf1.s, acc1[dt], 0, 0, 0);
            }
        }
        __syncthreads();
    }
    float inv0 = 1.0f / accl0[0], inv1 = 1.0f / accl1[0];
    size_t robase = ((size_t)b * HWN + N0 + lr) * CDIM + h * HDIM + g * 4;
#pragma unroll
    for (int dt = 0; dt < 4; ++dt) {
        uint2 o0 = {cvtpk(acc0[dt][0] * inv0, acc0[dt][1] * inv0),
                    cvtpk(acc0[dt][2] * inv0, acc0[dt][3] * inv0)};
        uint2 o1 = {cvtpk(acc1[dt][0] * inv1, acc1[dt][1] * inv1),
                    cvtpk(acc1[dt][2] * inv1, acc1[dt][3] * inv1)};
        *(uint2*)(attw + robase + dt * 16) = o0;
        *(uint2*)(attw + robase + 16 * CDIM + dt * 16) = o1;
    }
}

// ---------------- depthwise 3x3 conv + BN + add attended -> E (b,n,c) bf16 ----------------
// Block decode is XCD-aware: xcd=p&7 owns batches {2*xcd, 2*xcd+1} so the 32
// y-blocks sharing batch b's vw/attw working set land on one XCD (bijective).
__global__ __launch_bounds__(256) void conv_kernel(
    const unsigned short* __restrict__ vw,   // (b, c, n)
    const float* __restrict__ wpos, const float* __restrict__ gpos, const float* __restrict__ bpos,
    const unsigned short* __restrict__ attw, // (b, n, c)
    unsigned short* __restrict__ ew) {       // (b, n, c)
    __shared__ unsigned short po[32][520];   // [x][c], pad 520 (16B-aligned rows)
    int p = blockIdx.x;
    int xcd = p & 7, q = p >> 3;             // q in [0,64)
    int b = xcd * 2 + (q >> 5);
    int y = q & 31;
    int t = threadIdx.x;
#pragma unroll
    for (int hh = 0; hh < 2; ++hh) {
        int c = hh * 256 + t;
        const unsigned short* vrow = vw + ((size_t)(b * CDIM + c)) * HWN;
        uint4 rv[3][4];
#pragma unroll
        for (int dy = 0; dy < 3; ++dy) {
            int r = y + dy - 1;
            bool ok = (r >= 0) && (r < 32);
#pragma unroll
            for (int s2 = 0; s2 < 4; ++s2) {
                uint4 z = {0u, 0u, 0u, 0u};
                rv[dy][s2] = ok ? *(const uint4*)(vrow + r * 32 + s2 * 8) : z;
            }
        }
        float wreg[9];
#pragma unroll
        for (int k = 0; k < 9; ++k) wreg[k] = wpos[c * 9 + k];
        float gc = gpos[c], bc = bpos[c];
#pragma unroll
        for (int x = 0; x < 32; ++x) {
            float sum = 0.f;
#pragma unroll
            for (int dy = 0; dy < 3; ++dy)
#pragma unroll
                for (int dx = 0; dx < 3; ++dx) {
                    int xx = x + dx - 1;
                    if (xx >= 0 && xx < 32)
                        sum += wreg[dy * 3 + dx] * bfelem(rv[dy][xx >> 3], xx & 7);
                }
            po[x][c] = f2bf(sum * gc + bc);
        }
    }
    __syncthreads();
    int c8 = (t & 63) * 8;
    int xg = t >> 6;
#pragma unroll
    for (int i = 0; i < 8; ++i) {
        int x = xg + i * 4;
        size_t nidx = ((size_t)b * HWN + y * 32 + x) * CDIM + c8;
        uint4 a = *(const uint4*)(attw + nidx);
        uint4 pp = *(const uint4*)(&po[x][c8]);
        uint4 o = {addpk(a.x, pp.x), addpk(a.y, pp.y), addpk(a.z, pp.z), addpk(a.w, pp.w)};
        *(uint4*)(ew + nidx) = o;
    }
}

// ---------------- launch ----------------
extern "C" void kernel_launch(void* const* d_in, const int* in_sizes, int n_in,
                              void* d_out, int out_size, void* d_ws, size_t ws_size,
                              hipStream_t stream) {
    const float* x     = (const float*)d_in[0];
    const float* w_qkv = (const float*)d_in[1];
    const float* g_qkv = (const float*)d_in[2];
    const float* b_qkv = (const float*)d_in[3];
    const float* w_pos = (const float*)d_in[4];
    const float* g_pos = (const float*)d_in[5];
    const float* b_pos = (const float*)d_in[6];
    const float* w_out = (const float*)d_in[7];
    const float* g_out = (const float*)d_in[8];
    const float* b_out = (const float*)d_in[9];
    char* ws = (char*)d_ws;
    unsigned short* xt   = (unsigned short*)(ws);              // aliased as E later
    unsigned short* wqb  = (unsigned short*)(ws + 16777216);
    unsigned short* wob  = (unsigned short*)(ws + 17825792);
    unsigned short* qw   = (unsigned short*)(ws + 18350080);
    unsigned short* kw   = (unsigned short*)(ws + 26738688);
    unsigned short* vw   = (unsigned short*)(ws + 35127296);
    unsigned short* attw = (unsigned short*)(ws + 51904512);

    pre_kernel<<<2432, 256, 0, stream>>>(x, xt, w_qkv, wqb, w_out, wob);
    // gemm1: M=1024 (4 mtiles), BN=256 (4 ntiles/batch), BK=32 -> 64KB LDS, grid 256
    gemm_bf16<0, 256, 32, 2, 4, 4><<<256, 512, 0, stream>>>(wqb, xt, g_qkv, b_qkv, qw, kw, vw);
    attn_kernel<<<1024, 256, 0, stream>>>(qw, kw, vw, attw);
    conv_kernel<<<512, 256, 0, stream>>>(vw, w_pos, g_pos, b_pos, attw, xt /*E*/);
    // gemm2: M=512 (2 mtiles), BN=128 (8 ntiles/batch), BK=32 -> 48KB LDS, grid 256
    gemm_bf16<1, 128, 32, 4, 2, 8><<<256, 512, 0, stream>>>(wob, xt /*E*/, g_out, b_out, d_out, nullptr, nullptr);
}

// Round 20
// 130.961 us; speedup vs baseline: 1.0551x; 1.0551x over previous
//
#include <hip/hip_runtime.h>
#include <hip/hip_bf16.h>
#include <stdint.h>

// Problem constants
#define NHEADS 8
#define KDIM   32
#define HDIM   64
#define CDIM   512
#define HWN    1024
#define BATCH  16
#define QKVCH  1024
#define SCALE_F 0.17677669529663687f  // 32^-0.5
// q pre-scale: SCALE * log2(e), so softmax uses v_exp_f32 (2^x) directly
#define QSCALE_F (0.17677669529663687f * 1.44269504088896341f)

typedef __attribute__((ext_vector_type(8))) short short8;   // 8 bf16 (4 VGPRs)
typedef __attribute__((ext_vector_type(4))) float f32x4;

static __device__ __forceinline__ unsigned short f2bf(float f) {
    unsigned int u = __float_as_uint(f);
    unsigned int r = (u + 0x7fffu + ((u >> 16) & 1u)) >> 16;  // RNE
    return (unsigned short)r;
}
static __device__ __forceinline__ float bf2f(unsigned short h) {
    return __uint_as_float(((unsigned int)h) << 16);
}
// v_cvt_pk_bf16_f32: lo<-a, hi<-b (RNE), 1 instr for 2 converts
static __device__ __forceinline__ unsigned int cvtpk(float a, float b) {
    unsigned int r;
    asm("v_cvt_pk_bf16_f32 %0, %1, %2" : "=v"(r) : "v"(a), "v"(b));
    return r;
}
static __device__ __forceinline__ float fexp2(float x) {
    float r;
    asm("v_exp_f32 %0, %1" : "=v"(r) : "v"(x));
    return r;
}
// static-index bf16 extraction from a uint4 (8 bf16); j must be compile-time
static __device__ __forceinline__ float bfelem(const uint4& v, int j) {
    unsigned int w = ((j >> 1) == 0) ? v.x : ((j >> 1) == 1) ? v.y : ((j >> 1) == 2) ? v.z : v.w;
    return (j & 1) ? __uint_as_float(w & 0xffff0000u) : __uint_as_float(w << 16);
}
// add two bf16 pairs (packed u32) in fp32, repack
static __device__ __forceinline__ unsigned int addpk(unsigned int a, unsigned int p) {
    float lo = __uint_as_float(a << 16) + __uint_as_float(p << 16);
    float hi = __uint_as_float(a & 0xffff0000u) + __uint_as_float(p & 0xffff0000u);
    return cvtpk(lo, hi);
}

// async global->LDS, 16B per lane. LDS dest is wave-uniform base; HW adds lane*16.
static __device__ __forceinline__ void gload_lds16(const void* g, void* l) {
    __builtin_amdgcn_global_load_lds(
        (const __attribute__((address_space(1))) void*)g,
        (__attribute__((address_space(3))) void*)l, 16, 0, 0);
}

// ---------------- fused preprocessing: transpose + both weight converts ----------------
// blocks [0,2048): transpose x (b,c,n) fp32 -> xt (b,n,c) bf16
// blocks [2048,2304): convert w_qkv (524288 elems); [2304,2432): convert w_out (262144)
__global__ __launch_bounds__(256) void pre_kernel(
    const float* __restrict__ x, unsigned short* __restrict__ xt,
    const float* __restrict__ wq, unsigned short* __restrict__ wqb,
    const float* __restrict__ wo, unsigned short* __restrict__ wob) {
    __shared__ unsigned short tl[64][66];   // pad 66: odd word stride -> spread banks
    int bid = blockIdx.x;
    int t = threadIdx.x;
    if (bid < 2048) {
        int b = bid >> 7, ct = (bid >> 4) & 7, nt = bid & 15;
#pragma unroll
        for (int i = 0; i < 16; ++i) {
            int idx = i * 256 + t;
            int cl = idx >> 6, nl = idx & 63;
            tl[cl][nl] = f2bf(x[((size_t)(b * CDIM + ct * 64 + cl)) * HWN + nt * 64 + nl]);
        }
        __syncthreads();
        int a8 = (t & 7) * 8;
        int nl = t >> 3;
#pragma unroll
        for (int i = 0; i < 2; ++i) {
            int n = nt * 64 + nl + 32 * i;
            unsigned short tmp[8] __attribute__((aligned(16)));
#pragma unroll
            for (int j = 0; j < 8; ++j) tmp[j] = tl[a8 + j][nl + 32 * i];
            *(uint4*)(xt + ((size_t)b * HWN + n) * CDIM + ct * 64 + a8) = *(const uint4*)tmp;
        }
    } else {
        const float* src = (bid < 2304) ? wq : wo;
        unsigned short* dst = (bid < 2304) ? wqb : wob;
        int rb = (bid < 2304) ? (bid - 2048) : (bid - 2304);
        int i = (rb * 256 + t) * 8;
        float4 a = *(const float4*)(src + i);
        float4 c = *(const float4*)(src + i + 4);
        unsigned short r[8] __attribute__((aligned(16))) =
            {f2bf(a.x), f2bf(a.y), f2bf(a.z), f2bf(a.w), f2bf(c.x), f2bf(c.y), f2bf(c.z), f2bf(c.w)};
        *(uint4*)(dst + i) = *(const uint4*)r;
    }
}

// ---------------- bf16 GEMM, BM=256 x BN tile, templated BK, 8 waves (512 thr) ----------------
// Treats the batched problem as M x (16*1024) columns. A: (M x 512) bf16 weights.
// Bt: (16, 1024, 512) bf16 (K contig). D[o][b,n] = sum_k A[o][k]*Bt[n][k].
// Fragment-ordered LDS (lane-linear ds_read_b128, 0 conflicts), double-buffered.
// BK=32 + BN=256 (best measured config: 64 MFMA/barrier; tile-shrink variants
// BN=128 (R17) and attn KVBLK=64 (R19) both regressed -> never shrink the tile).
// T1: xcd = p&7 owns batches {2*xcd, 2*xcd+1} -> B-panels L2-resident per XCD.
template <int MODE, int BN, int BK, int WM, int WN, int NTB>
__global__ __launch_bounds__(512, 2) void gemm_bf16(
    const unsigned short* __restrict__ A, const unsigned short* __restrict__ Bt,
    const float* __restrict__ gvec, const float* __restrict__ bvec,
    void* out0, void* out1, void* out2) {
    constexpr int MF = 256 / (16 * WM);      // m-frags per wave
    constexpr int NF = BN / (16 * WN);       // n-frags per wave
    constexpr int BUFE = (256 + BN) * BK;    // elems per LDS buffer
    constexpr int AIT = BK / 16;             // stage_a loop count (A units = 32*BK)
    constexpr int BUNITS = BN * BK / 4096;   // stage_b loop count
    constexpr int PHB = BN * 4;              // B units per 32-k half
    constexpr int AELEMS = 256 * BK;         // A region elems
    constexpr int KT = 512 / BK;             // K-tiles
    __shared__ unsigned short lds[2][BUFE];

    int p = blockIdx.x;
    int xcd = p & 7;
    int j2 = p >> 3;                         // 0..31
    int b = xcd * 2 + (j2 >= 16 ? 1 : 0);
    int idx = j2 & 15;
    int mt = idx / NTB, ntl = idx % NTB;
    int t = threadIdx.x, lane = t & 63, w = t >> 6, g = lane >> 4, lr = lane & 15;
    int M0 = mt * 256, N0 = ntl * BN;
    int wr = (w / WN) * (16 * MF), wc = (w % WN) * (16 * NF);

    const unsigned short* Ab = A + (size_t)M0 * 512;
    const unsigned short* Bb = Bt + (size_t)b * HWN * 512 + (size_t)N0 * 512;

    auto stage_a = [&](int kt, int buf) {
        unsigned short* base = &lds[buf][0];
#pragma unroll
        for (int i = 0; i < AIT; ++i) {      // A: 256 x BK
            int U0 = i * 512 + w * 64;
            int U = U0 + lane;
            int h = U >> 10, rem = U & 1023;
            int row = ((rem >> 6) << 4) + (lane & 15);
            int k = ((lane >> 4) << 3) + (h << 5);
            gload_lds16(Ab + (size_t)row * 512 + kt * BK + k, (char*)base + U0 * 16);
        }
    };
    auto stage_b = [&](int kt, int buf) {
        unsigned short* base = &lds[buf][0];
#pragma unroll
        for (int i = 0; i < BUNITS; ++i) {   // B: BN x BK
            int U0 = i * 512 + w * 64;
            int U = U0 + lane;
            int h = U / PHB, rem = U % PHB;
            int row = ((rem >> 6) << 4) + (lane & 15);
            int k = ((lane >> 4) << 3) + (h << 5);
            gload_lds16(Bb + (size_t)row * 512 + kt * BK + k,
                        (char*)base + AELEMS * 2 + U0 * 16);
        }
    };

    f32x4 acc[MF][NF] = {};
    stage_a(0, 0);
    stage_b(0, 0);
    __syncthreads();
    for (int kt = 0; kt < KT; ++kt) {
        int cur = kt & 1;
        const unsigned short* base = &lds[cur][0];
        auto compute_h = [&](int h) {
            short8 af[MF], bfr[NF];
#pragma unroll
            for (int i = 0; i < MF; ++i)
                af[i] = *(const short8*)(base + h * 8192 + (((wr >> 4) + i) * 64 + lane) * 8);
#pragma unroll
            for (int j = 0; j < NF; ++j)
                bfr[j] = *(const short8*)(base + AELEMS + h * (BN * 32) +
                                          (((wc >> 4) + j) * 64 + lane) * 8);
#pragma unroll
            for (int i = 0; i < MF; ++i)
#pragma unroll
                for (int j = 0; j < NF; ++j)
                    acc[i][j] = __builtin_amdgcn_mfma_f32_16x16x32_bf16(af[i], bfr[j], acc[i][j], 0, 0, 0);
        };
        if constexpr (BK == 64) {
            if (kt < KT - 1) stage_a(kt + 1, cur ^ 1);
            compute_h(0);
            if (kt < KT - 1) stage_b(kt + 1, cur ^ 1);
            compute_h(1);
        } else {
            if (kt < KT - 1) { stage_a(kt + 1, cur ^ 1); stage_b(kt + 1, cur ^ 1); }
            compute_h(0);
        }
        __syncthreads();
    }

#pragma unroll
    for (int i = 0; i < MF; ++i) {
        int obase = M0 + wr + i * 16 + g * 4;
#pragma unroll
        for (int j = 0; j < NF; ++j) {
            int n = N0 + wc + j * 16 + lr;
            float val[4];
#pragma unroll
            for (int rr = 0; rr < 4; ++rr) {
                int o = obase + rr;
                val[rr] = acc[i][j][rr] * gvec[o] + bvec[o];
            }
            if (MODE == 0) {
                int h = obase >> 7, jj = obase & 127;
                size_t bh = (size_t)((b << 3) + h);
                if (jj < 32) {
                    uint2 pk = {cvtpk(val[0] * QSCALE_F, val[1] * QSCALE_F),
                                cvtpk(val[2] * QSCALE_F, val[3] * QSCALE_F)};
                    *(uint2*)((unsigned short*)out0 + (bh * HWN + n) * KDIM + jj) = pk;
                } else if (jj < 64) {
                    uint2 pk = {cvtpk(val[0], val[1]), cvtpk(val[2], val[3])};
                    *(uint2*)((unsigned short*)out1 + (bh * HWN + n) * KDIM + (jj - 32)) = pk;
                } else {
#pragma unroll
                    for (int rr = 0; rr < 4; ++rr)
                        ((unsigned short*)out2)[(bh * HDIM + (jj - 64 + rr)) * HWN + n] = f2bf(val[rr]);
                }
            } else {
#pragma unroll
                for (int rr = 0; rr < 4; ++rr)
                    ((float*)out0)[((size_t)(b * CDIM + obase + rr)) * HWN + n] = val[rr];
            }
        }
    }
}

// ---------------- flash attention (no-max softmax, 2 q-frags/wave) ----------------
// R14/R16/R18 session-best structure (4 waves, 256 thr, grid 1024; KVBLK=128
// K fragment-ordered LDS staging -- KVBLK=64 variant regressed, R19). l is
// accumulated on the MATRIX pipe: one mfma(ones, pf, accl) per q-frag per
// mc-step (A=ones(16x32) -> D[r][c] = sum_k P[k][c]); each lane's accl[0] is
// l for its q-column (col = lane&15) -> no VALU add chain, no shuffles.
// q/k: (bh, n, 32) bf16 (SCALE*log2e folded into q). v: (bh, 64, 1024) bf16.
// S^T = mfma(Kfrag, Qfrag) so P sits directly in PV's B-operand layout.
// K LDS: fragment-ordered (lane-linear b128 reads). V LDS: (d&7)<<4 XOR swizzle.
// XCD swizzle: physical p -> bh = ((p>>6)<<3)|(p&7), ntile = (p>>3)&7, so all 8
// ntile-blocks of one bh satisfy p % 8 == bh % 8 -> same XCD -> K/V L2-resident.
// Output: attw (b, n, c=h*64+d) bf16.
__global__ __launch_bounds__(256) void attn_kernel(
    const unsigned short* __restrict__ qw, const unsigned short* __restrict__ kw,
    const unsigned short* __restrict__ vw, unsigned short* __restrict__ attw) {
    __shared__ unsigned short kt[2][128 * 32];   // 2 x 8KB
    __shared__ unsigned short vt[2][64 * 128];   // 2 x 16KB
    int p = blockIdx.x;
    int bh = ((p >> 6) << 3) | (p & 7);
    int ntile = (p >> 3) & 7;
    int b = bh >> 3, h = bh & 7;
    int t = threadIdx.x, lane = t & 63, w = t >> 6, g = lane >> 4, lr = lane & 15;
    int N0 = ntile * 128 + w * 32;
    const unsigned short* qb = qw + (size_t)bh * HWN * KDIM;
    const unsigned short* kb = kw + (size_t)bh * HWN * KDIM;
    const unsigned short* vb = vw + (size_t)bh * HDIM * HWN;

    short8 qf0 = *(const short8*)(qb + (size_t)(N0 + lr) * KDIM + g * 8);
    short8 qf1 = *(const short8*)(qb + (size_t)(N0 + 16 + lr) * KDIM + g * 8);
    f32x4 acc0[4] = {}, acc1[4] = {};
    f32x4 accl0 = {}, accl1 = {};
    f32x4 zero = {0.f, 0.f, 0.f, 0.f};
    short8 onesv;
#pragma unroll
    for (int i = 0; i < 8; ++i) onesv[i] = (short)0x3F80;   // bf16 1.0
    int sw = (lr & 7) << 4;      // V swizzle, constant per lane
    int g8 = g << 3;

    auto stage = [&](int mt, int buf) {
        int M0 = mt * 128;
#pragma unroll
        for (int pp = 0; pp < 2; ++pp) {   // K: fragment-ordered
            int s = pp * 256 + w * 64 + lane;
            int row = (s >> 7) * 32 + ((s >> 6) & 1) * 16 + lr;
            gload_lds16(kb + (size_t)(M0 + row) * KDIM + g * 8,
                        (char*)kt[buf] + (pp * 4 + w) * 1024);
        }
#pragma unroll
        for (int pp = 0; pp < 4; ++pp) {   // V: XOR-swizzled via pre-swizzled source
            int s = pp * 256 + w * 64 + lane;
            int dd = s >> 4, u = s & 15;
            gload_lds16(vb + (size_t)dd * HWN + M0 + ((u ^ (dd & 7)) << 3),
                        (char*)vt[buf] + (pp * 4 + w) * 1024);
        }
    };

    stage(0, 0);
    __syncthreads();
    for (int mt = 0; mt < 8; ++mt) {
        int cur = mt & 1;
        if (mt < 7) stage(mt + 1, cur ^ 1);
        const char* ktc = (const char*)kt[cur] + lane * 16;
        const char* vrow = (const char*)vt[cur] + lr * 256;
#pragma unroll
        for (int mc = 0; mc < 4; ++mc) {
            short8 kf0 = *(const short8*)(ktc + mc * 2048);
            short8 kf1 = *(const short8*)(ktc + mc * 2048 + 1024);
            f32x4 s00 = __builtin_amdgcn_mfma_f32_16x16x32_bf16(kf0, qf0, zero, 0, 0, 0);
            f32x4 s01 = __builtin_amdgcn_mfma_f32_16x16x32_bf16(kf1, qf0, zero, 0, 0, 0);
            f32x4 s10 = __builtin_amdgcn_mfma_f32_16x16x32_bf16(kf0, qf1, zero, 0, 0, 0);
            f32x4 s11 = __builtin_amdgcn_mfma_f32_16x16x32_bf16(kf1, qf1, zero, 0, 0, 0);
            float e0[8], e1[8];
#pragma unroll
            for (int i = 0; i < 4; ++i) {
                e0[i] = fexp2(s00[i]); e0[4 + i] = fexp2(s01[i]);
                e1[i] = fexp2(s10[i]); e1[4 + i] = fexp2(s11[i]);
            }
            union { uint4 u; short8 s; } pf0, pf1;
            pf0.u = (uint4){cvtpk(e0[0], e0[1]), cvtpk(e0[2], e0[3]),
                            cvtpk(e0[4], e0[5]), cvtpk(e0[6], e0[7])};
            pf1.u = (uint4){cvtpk(e1[0], e1[1]), cvtpk(e1[2], e1[3]),
                            cvtpk(e1[4], e1[5]), cvtpk(e1[6], e1[7])};
            accl0 = __builtin_amdgcn_mfma_f32_16x16x32_bf16(onesv, pf0.s, accl0, 0, 0, 0);
            accl1 = __builtin_amdgcn_mfma_f32_16x16x32_bf16(onesv, pf1.s, accl1, 0, 0, 0);
            int off0 = (mc * 64 + g8) ^ sw;
            int off1 = off0 ^ 32;
#pragma unroll
            for (int dt = 0; dt < 4; ++dt) {
                uint2 v0 = *(const uint2*)(vrow + dt * 4096 + off0);
                uint2 v1 = *(const uint2*)(vrow + dt * 4096 + off1);
                union { uint2 u[2]; short8 s; } vf;
                vf.u[0] = v0; vf.u[1] = v1;
                acc0[dt] = __builtin_amdgcn_mfma_f32_16x16x32_bf16(vf.s, pf0.s, acc0[dt], 0, 0, 0);
                acc1[dt] = __builtin_amdgcn_mfma_f32_16x16x32_bf16(vf.s, pf1.s, acc1[dt], 0, 0, 0);
            }
        }
        __syncthreads();
    }
    float inv0 = 1.0f / accl0[0], inv1 = 1.0f / accl1[0];
    size_t robase = ((size_t)b * HWN + N0 + lr) * CDIM + h * HDIM + g * 4;
#pragma unroll
    for (int dt = 0; dt < 4; ++dt) {
        uint2 o0 = {cvtpk(acc0[dt][0] * inv0, acc0[dt][1] * inv0),
                    cvtpk(acc0[dt][2] * inv0, acc0[dt][3] * inv0)};
        uint2 o1 = {cvtpk(acc1[dt][0] * inv1, acc1[dt][1] * inv1),
                    cvtpk(acc1[dt][2] * inv1, acc1[dt][3] * inv1)};
        *(uint2*)(attw + robase + dt * 16) = o0;
        *(uint2*)(attw + robase + 16 * CDIM + dt * 16) = o1;
    }
}

// ---------------- depthwise 3x3 conv + BN + add attended -> E (b,n,c) bf16 ----------------
// Block decode is XCD-aware: xcd=p&7 owns batches {2*xcd, 2*xcd+1} so the 32
// y-blocks sharing batch b's vw/attw working set land on one XCD (bijective).
__global__ __launch_bounds__(256) void conv_kernel(
    const unsigned short* __restrict__ vw,   // (b, c, n)
    const float* __restrict__ wpos, const float* __restrict__ gpos, const float* __restrict__ bpos,
    const unsigned short* __restrict__ attw, // (b, n, c)
    unsigned short* __restrict__ ew) {       // (b, n, c)
    __shared__ unsigned short po[32][520];   // [x][c], pad 520 (16B-aligned rows)
    int p = blockIdx.x;
    int xcd = p & 7, q = p >> 3;             // q in [0,64)
    int b = xcd * 2 + (q >> 5);
    int y = q & 31;
    int t = threadIdx.x;
#pragma unroll
    for (int hh = 0; hh < 2; ++hh) {
        int c = hh * 256 + t;
        const unsigned short* vrow = vw + ((size_t)(b * CDIM + c)) * HWN;
        uint4 rv[3][4];
#pragma unroll
        for (int dy = 0; dy < 3; ++dy) {
            int r = y + dy - 1;
            bool ok = (r >= 0) && (r < 32);
#pragma unroll
            for (int s2 = 0; s2 < 4; ++s2) {
                uint4 z = {0u, 0u, 0u, 0u};
                rv[dy][s2] = ok ? *(const uint4*)(vrow + r * 32 + s2 * 8) : z;
            }
        }
        float wreg[9];
#pragma unroll
        for (int k = 0; k < 9; ++k) wreg[k] = wpos[c * 9 + k];
        float gc = gpos[c], bc = bpos[c];
#pragma unroll
        for (int x = 0; x < 32; ++x) {
            float sum = 0.f;
#pragma unroll
            for (int dy = 0; dy < 3; ++dy)
#pragma unroll
                for (int dx = 0; dx < 3; ++dx) {
                    int xx = x + dx - 1;
                    if (xx >= 0 && xx < 32)
                        sum += wreg[dy * 3 + dx] * bfelem(rv[dy][xx >> 3], xx & 7);
                }
            po[x][c] = f2bf(sum * gc + bc);
        }
    }
    __syncthreads();
    int c8 = (t & 63) * 8;
    int xg = t >> 6;
#pragma unroll
    for (int i = 0; i < 8; ++i) {
        int x = xg + i * 4;
        size_t nidx = ((size_t)b * HWN + y * 32 + x) * CDIM + c8;
        uint4 a = *(const uint4*)(attw + nidx);
        uint4 pp = *(const uint4*)(&po[x][c8]);
        uint4 o = {addpk(a.x, pp.x), addpk(a.y, pp.y), addpk(a.z, pp.z), addpk(a.w, pp.w)};
        *(uint4*)(ew + nidx) = o;
    }
}

// ---------------- launch ----------------
extern "C" void kernel_launch(void* const* d_in, const int* in_sizes, int n_in,
                              void* d_out, int out_size, void* d_ws, size_t ws_size,
                              hipStream_t stream) {
    const float* x     = (const float*)d_in[0];
    const float* w_qkv = (const float*)d_in[1];
    const float* g_qkv = (const float*)d_in[2];
    const float* b_qkv = (const float*)d_in[3];
    const float* w_pos = (const float*)d_in[4];
    const float* g_pos = (const float*)d_in[5];
    const float* b_pos = (const float*)d_in[6];
    const float* w_out = (const float*)d_in[7];
    const float* g_out = (const float*)d_in[8];
    const float* b_out = (const float*)d_in[9];
    char* ws = (char*)d_ws;
    unsigned short* xt   = (unsigned short*)(ws);              // aliased as E later
    unsigned short* wqb  = (unsigned short*)(ws + 16777216);
    unsigned short* wob  = (unsigned short*)(ws + 17825792);
    unsigned short* qw   = (unsigned short*)(ws + 18350080);
    unsigned short* kw   = (unsigned short*)(ws + 26738688);
    unsigned short* vw   = (unsigned short*)(ws + 35127296);
    unsigned short* attw = (unsigned short*)(ws + 51904512);

    pre_kernel<<<2432, 256, 0, stream>>>(x, xt, w_qkv, wqb, w_out, wob);
    // gemm1: M=1024 (4 mtiles), BN=256 (4 ntiles/batch), BK=32 -> 64KB LDS, grid 256
    gemm_bf16<0, 256, 32, 2, 4, 4><<<256, 512, 0, stream>>>(wqb, xt, g_qkv, b_qkv, qw, kw, vw);
    attn_kernel<<<1024, 256, 0, stream>>>(qw, kw, vw, attw);
    conv_kernel<<<512, 256, 0, stream>>>(vw, w_pos, g_pos, b_pos, attw, xt /*E*/);
    // gemm2: M=512 (2 mtiles), BN=128 (8 ntiles/batch), BK=32 -> 48KB LDS, grid 256
    gemm_bf16<1, 128, 32, 4, 2, 8><<<256, 512, 0, stream>>>(wob, xt /*E*/, g_out, b_out, d_out, nullptr, nullptr);
}